// Round 4
// baseline (7203.623 us; speedup 1.0000x reference)
//
#include <hip/hip_runtime.h>
#include <stdint.h>

typedef unsigned short ushort_t;
typedef unsigned long long u64;
typedef __attribute__((ext_vector_type(8))) short short8;
typedef __attribute__((ext_vector_type(4))) float f32x4;
typedef __attribute__((ext_vector_type(2))) float f32x2;

#define T_SEQ 3300
#define SENT 0x7FC00001u
#define SENTPAIR 0x7FC000017FC00001ull

__device__ __forceinline__ ushort_t f2b(float f) {
  uint32_t u = __float_as_uint(f);
  u = (u + 0x7fffu + ((u >> 16) & 1u)) >> 16;
  return (ushort_t)u;
}
__device__ __forceinline__ float b2f(ushort_t b) {
  return __uint_as_float(((uint32_t)b) << 16);
}

// ---- local (intra-XCD) comm ops: sc0 = bypass L1, served by the XCD L2 ----
__device__ __forceinline__ f32x4 ld16_loc(const void* p) {
  f32x4 r;
  asm volatile("global_load_dwordx4 %0, %1, off sc0\n\ts_waitcnt vmcnt(0)"
               : "=v"(r) : "v"(p) : "memory");
  return r;
}
__device__ __forceinline__ uint32_t ld32_loc(const void* p) {
  uint32_t r;
  asm volatile("global_load_dword %0, %1, off sc0\n\ts_waitcnt vmcnt(0)"
               : "=v"(r) : "v"(p) : "memory");
  return r;
}
__device__ __forceinline__ void st32_loc(void* p, uint32_t v) {
  asm volatile("global_store_dword %0, %1, off sc0" :: "v"(p), "v"(v) : "memory");
}
__device__ __forceinline__ void st8_loc(void* p, u64 v) {
  asm volatile("global_store_dwordx2 %0, %1, off sc0" :: "v"(p), "v"(v) : "memory");
}

// ---------------- prep: weight transpose/convert + sentinel init ------------
__global__ void prep_kernel(const float* __restrict__ w_ih,
                            const float* __restrict__ fc1w,
                            const float* __restrict__ fc2w,
                            ushort_t* __restrict__ w_ihT,
                            ushort_t* __restrict__ fc1wb,
                            ushort_t* __restrict__ fc2wb,
                            uint32_t* __restrict__ h_ring,
                            uint32_t* __restrict__ pctl) {
  int i = blockIdx.x * 256 + threadIdx.x;
  if (i < 512 * 1536) {            // w_ihT[d][g] = w_ih[g][d], d<512 (one-hot rows)
    int d = i / 1536, g = i - d * 1536;
    w_ihT[i] = f2b(w_ih[g * 592 + d]);
  }
  int j = i - 512 * 1536;
  if (j >= 0 && j < 262144) fc1wb[j] = f2b(fc1w[j]);
  int k = j - 262144;
  if (k >= 0 && k < 262144) fc2wb[k] = f2b(fc2w[k]);
  int c = k - 262144;
  if (c >= 0 && c < 131072) {
    // sentinel to the coherence point (bypasses L2s)
    __hip_atomic_store(&h_ring[c], SENT, __ATOMIC_RELAXED, __HIP_MEMORY_SCOPE_AGENT);
  }
  int c2 = c - 131072;
  if (c2 >= 0 && c2 < 768) {
    __hip_atomic_store(&pctl[c2], SENT, __ATOMIC_RELAXED, __HIP_MEMORY_SCOPE_AGENT);
  }
}

// ---------------- upsample: repeat+box-filter cascade, one block per (b,f) --
__global__ void upsample_kernel(const float* __restrict__ mels,
                                const float* __restrict__ k0,
                                const float* __restrict__ k1,
                                const float* __restrict__ k2,
                                float* __restrict__ mels_up) {
  __shared__ float s0[16];
  __shared__ float s1[80];
  __shared__ float s2[400];
  int bf = blockIdx.x;
  int b = bf / 80, f = bf - b * 80;
  int tid = threadIdx.x;  // 128
  float c0 = k0[0], c1 = k1[0], c2 = k2[0];
  if (tid < 16) s0[tid] = mels[(b * 80 + f) * 16 + tid];
  __syncthreads();
  if (tid < 80) {
    float a = 0.f;
    #pragma unroll
    for (int d = -5; d <= 5; ++d) {
      int w = tid + d;
      if (w >= 0 && w < 80) a += s0[w / 5];
    }
    s1[tid] = a * c0;
  }
  __syncthreads();
  for (int w = tid; w < 400; w += 128) {
    float a = 0.f;
    #pragma unroll
    for (int d = -5; d <= 5; ++d) {
      int u = w + d;
      if (u >= 0 && u < 400) a += s1[u / 5];
    }
    s2[w] = a * c1;
  }
  __syncthreads();
  for (int t = tid; t < T_SEQ; t += 128) {
    int wb = 550 + t;   // wb+d in [539,3860] -> /11 < 400: no bounds needed
    float a = 0.f;
    #pragma unroll
    for (int d = -11; d <= 11; ++d) a += s2[(wb + d) / 11];
    mels_up[(b * 80 + f) * T_SEQ + t] = a * c2;
  }
}

// ---- 32-lane sum: DPP row_shr cascade (16) + shfl_xor 16. Valid on lane cc==15 (and 31).
__device__ __forceinline__ float red32(float x) {
  x += __uint_as_float((uint32_t)__builtin_amdgcn_update_dpp(0, (int)__float_as_uint(x), 0x111, 0xf, 0xf, true));
  x += __uint_as_float((uint32_t)__builtin_amdgcn_update_dpp(0, (int)__float_as_uint(x), 0x112, 0xf, 0xf, true));
  x += __uint_as_float((uint32_t)__builtin_amdgcn_update_dpp(0, (int)__float_as_uint(x), 0x114, 0xf, 0xf, true));
  x += __uint_as_float((uint32_t)__builtin_amdgcn_update_dpp(0, (int)__float_as_uint(x), 0x118, 0xf, 0xf, true));
  x += __shfl_xor(x, 16, 64);
  return x;
}

// ---------------- persistent GRU --------------------------------------------
// 256 blocks x 512 threads. Group = batch b (16 blocks); block j owns h dims [32j,32j+32).
// Comm default: relaxed AGENT atomics (cache-bypassing, correct on any mapping).
// One-time VERIFIED upgrade to sc0-local (single-XCD L2) comm via a handshake
// probe: members exchange tokens over the sc0 path under a wall-clock deadline;
// cross-XCD members cache the stale pre-token line and MUST time out. Verdicts
// are exchanged over the always-correct global path; only unanimous groups
// switch. Any anomaly degrades to the proven Round-2 global protocol.
__global__ __launch_bounds__(512) void gru_kernel(
    const int* __restrict__ x,
    const float* __restrict__ mels_up,
    const float* __restrict__ w_ih,
    const float* __restrict__ w_hh,
    const float* __restrict__ b_ih,
    const float* __restrict__ b_hh,
    const ushort_t* __restrict__ w_ihT,
    uint32_t* __restrict__ h_ring,  // [16][16][512] fp32 bits
    uint32_t* __restrict__ pctl,    // [3][16][16]: sync0 / probe / verdict
    ushort_t* __restrict__ h_seq)   // [16][3300][512] bf16
{
  int blk = blockIdx.x;
  int xcd = blk & 7, slot = blk >> 3;
  int b = (xcd << 1) | (slot >> 4);   // heuristic mapping; PROBE verifies locality
  int j = slot & 15;
  int tid = threadIdx.x;
  int cc = tid & 31, rr = tid >> 5;

  __shared__ __align__(16) float v[640];    // [0,512)=h, [512,592)=mel, rest 0
  __shared__ float embs[96];
  __shared__ int s_local;

  if (tid < 48) v[592 + tid] = 0.f;

  // ---- load resident weights (packed f32x2 for v_pk_fma_f32) ----
  f32x2 w2[6][10];
  float wmel[2][3];
  float bsum[4], bihn[2], bhhn[2];
  #pragma unroll
  for (int q = 0; q < 6; ++q) {
    int gate = q >> 1, kk = q & 1;
    int g = gate * 512 + j * 32 + rr * 2 + kk;
    #pragma unroll
    for (int cl = 0; cl < 10; ++cl) {
      f32x2 wv = {0.f, 0.f};
      #pragma unroll
      for (int e = 0; e < 2; ++e) {
        int col = cc * 20 + cl * 2 + e;
        float val = 0.f;
        if (col < 512) val = w_hh[g * 512 + col];
        else if (col < 592 && gate < 2) val = w_ih[g * 592 + col]; // mel (r,z only)
        wv[e] = val;
      }
      w2[q][cl] = wv;
    }
  }
  #pragma unroll
  for (int kk = 0; kk < 2; ++kk) {
    int g = 1024 + j * 32 + rr * 2 + kk;
    #pragma unroll
    for (int ii = 0; ii < 3; ++ii) {
      int fidx = cc * 3 + ii;
      wmel[kk][ii] = (fidx < 80) ? w_ih[g * 592 + 512 + fidx] : 0.f;
    }
    bihn[kk] = b_ih[g];
    bhhn[kk] = b_hh[g];
  }
  #pragma unroll
  for (int q = 0; q < 4; ++q) {
    int gate = q >> 1, kk = q & 1;
    int g = gate * 512 + j * 32 + rr * 2 + kk;
    bsum[q] = b_ih[g] + b_hh[g];
  }

  // ---- locality probe (tid 0 only) ----
  if (tid == 0) {
    uint32_t* sync0 = pctl + b * 16;
    uint32_t* probe = pctl + 256 + b * 16;
    uint32_t* verd  = pctl + 512 + b * 16;
    // Phase A: align group members (always-correct global path)
    __hip_atomic_store(&sync0[j], 1u, __ATOMIC_RELAXED, __HIP_MEMORY_SCOPE_AGENT);
    for (int kq = 0; kq < 16; ++kq)
      while (__hip_atomic_load(&sync0[kq], __ATOMIC_RELAXED, __HIP_MEMORY_SCOPE_AGENT) == SENT) {}
    // Phase B: token over the sc0 path, deadline-bounded poll
    st32_loc(&probe[j], 1u);
    u64 t0 = __builtin_amdgcn_s_memrealtime();
    int ok = 0;
    for (;;) {
      int seen = 1;
      for (int kq = 0; kq < 16; ++kq)
        if (ld32_loc(&probe[kq]) == SENT) { seen = 0; break; }
      if (seen) { ok = 1; break; }
      if (__builtin_amdgcn_s_memrealtime() - t0 > 4000) break;  // ~40us @100MHz
    }
    // Phase C: unanimous verdict over the global path
    __hip_atomic_store(&verd[j], ok ? 1u : 2u, __ATOMIC_RELAXED, __HIP_MEMORY_SCOPE_AGENT);
    int allok = 1;
    for (int kq = 0; kq < 16; ++kq) {
      uint32_t vv;
      do { vv = __hip_atomic_load(&verd[kq], __ATOMIC_RELAXED, __HIP_MEMORY_SCOPE_AGENT); }
      while (vv == SENT);
      if (vv != 1u) allok = 0;
    }
    s_local = allok;
  }
  __syncthreads();
  int local = s_local;

  for (int t = 0; t < T_SEQ; ++t) {
    // ---- prefetch (independent of h; plain cached loads) ----
    float melv = 0.f;
    if (tid < 80) melv = mels_up[(b * 80 + tid) * T_SEQ + t];
    float embv = 0.f;
    if (tid < 96) {
      int xv = x[b * T_SEQ + t];
      int gate = tid >> 5, kl = tid & 31;
      embv = b2f(w_ihT[xv * 1536 + gate * 512 + j * 32 + kl]);
    }
    // ---- poll h_{t-1} on data (sentinel = not ready) ----
    f32x4 hq = {0.f, 0.f, 0.f, 0.f};
    if (t > 0 && tid < 128) {
      int rslot = (t - 1) & 15;
      const uint32_t* src = &h_ring[((rslot * 16 + b) * 512) + tid * 4];
      if (local) {
        for (;;) {
          hq = ld16_loc(src);
          if (__float_as_uint(hq[0]) != SENT && __float_as_uint(hq[1]) != SENT &&
              __float_as_uint(hq[2]) != SENT && __float_as_uint(hq[3]) != SENT) break;
        }
      } else {
        const u64* s8 = (const u64*)src;
        u64 q0, q1;
        for (;;) {
          q0 = __hip_atomic_load(s8,     __ATOMIC_RELAXED, __HIP_MEMORY_SCOPE_AGENT);
          q1 = __hip_atomic_load(s8 + 1, __ATOMIC_RELAXED, __HIP_MEMORY_SCOPE_AGENT);
          if (((uint32_t)q0) != SENT && ((uint32_t)(q0 >> 32)) != SENT &&
              ((uint32_t)q1) != SENT && ((uint32_t)(q1 >> 32)) != SENT) break;
        }
        hq[0] = __uint_as_float((uint32_t)q0);
        hq[1] = __uint_as_float((uint32_t)(q0 >> 32));
        hq[2] = __uint_as_float((uint32_t)q1);
        hq[3] = __uint_as_float((uint32_t)(q1 >> 32));
      }
    }
    // ---- stage v = [h | mel] and emb into LDS ----
    if (tid < 128) *(f32x4*)&v[tid * 4] = hq;
    if (tid < 80) v[512 + tid] = melv;
    if (tid < 96) embs[tid] = embv;
    __syncthreads();

    // ---- matvec: acc[q] = sum_cols v[col]*W[row(q)][col]  (packed fp32) ----
    f32x2 hv2[10];
    #pragma unroll
    for (int s = 0; s < 5; ++s) {
      f32x4 t4 = *(const f32x4*)&v[cc * 20 + s * 4];
      hv2[s * 2]     = (f32x2){t4[0], t4[1]};
      hv2[s * 2 + 1] = (f32x2){t4[2], t4[3]};
    }
    f32x2 p0 = {0.f,0.f}, p1 = {0.f,0.f}, p2 = {0.f,0.f};
    f32x2 p3 = {0.f,0.f}, p4 = {0.f,0.f}, p5 = {0.f,0.f};
    #pragma unroll
    for (int cl = 0; cl < 10; ++cl) {
      f32x2 hvv = hv2[cl];
      p0 += hvv * w2[0][cl]; p1 += hvv * w2[1][cl];
      p2 += hvv * w2[2][cl]; p3 += hvv * w2[3][cl];
      p4 += hvv * w2[4][cl]; p5 += hvv * w2[5][cl];
    }
    float a0 = p0[0] + p0[1], a1 = p1[0] + p1[1], a2 = p2[0] + p2[1];
    float a3 = p3[0] + p3[1], a4 = p4[0] + p4[1], a5 = p5[0] + p5[1];
    float am0 = 0.f, am1 = 0.f;   // n-gate x-side mel part (kept separate from h-side)
    #pragma unroll
    for (int ii = 0; ii < 3; ++ii) {
      float mv = v[512 + cc * 3 + ii];
      am0 += mv * wmel[0][ii]; am1 += mv * wmel[1][ii];
    }
    float r0 = red32(a0), r1 = red32(a1), r2 = red32(a2);
    float r3 = red32(a3), r4 = red32(a4), r5 = red32(a5);
    float rm0 = red32(am0), rm1 = red32(am1);

    if (cc == 15) {
      float hn2[2];
      #pragma unroll
      for (int kk = 0; kk < 2; ++kk) {
        float sr  = kk ? r1 : r0;
        float sz  = kk ? r3 : r2;
        float sn  = kk ? r5 : r4;
        float smn = kk ? rm1 : rm0;
        int k = rr * 2 + kk;
        float ar = embs[k] + sr + bsum[0 + kk];
        float az = embs[32 + k] + sz + bsum[2 + kk];
        float rg = 1.f / (1.f + __expf(-ar));
        float zg = 1.f / (1.f + __expf(-az));
        float xn = embs[64 + k] + smn + bihn[kk];
        float hn = sn + bhhn[kk];
        float na = xn + rg * hn;
        float e2 = __expf(2.f * na);
        float ng = 1.f - 2.f / (e2 + 1.f);   // tanh
        float hp = v[j * 32 + k];
        hn2[kk] = (1.f - zg) * ng + zg * hp;
      }
      // publish h_t; re-arm slot t+8 (8-step slack covers retirement ordering)
      int wslot = t & 15;
      int aslot = (t + 8) & 15;
      u64 pk = ((u64)__float_as_uint(hn2[1]) << 32) | (u64)__float_as_uint(hn2[0]);
      u64* dst  = (u64*)&h_ring[((wslot * 16 + b) * 512) + j * 32 + rr * 2];
      u64* adst = (u64*)&h_ring[((aslot * 16 + b) * 512) + j * 32 + rr * 2];
      if (local) {
        st8_loc(dst, pk);
        st8_loc(adst, SENTPAIR);
      } else {
        __hip_atomic_store(dst,  pk,       __ATOMIC_RELAXED, __HIP_MEMORY_SCOPE_AGENT);
        __hip_atomic_store(adst, SENTPAIR, __ATOMIC_RELAXED, __HIP_MEMORY_SCOPE_AGENT);
      }
      // h_seq for the head (plain cached store; kernel boundary makes it visible)
      uint32_t hb = (uint32_t)f2b(hn2[0]) | ((uint32_t)f2b(hn2[1]) << 16);
      *(uint32_t*)&h_seq[(size_t)(b * T_SEQ + t) * 512 + j * 32 + rr * 2] = hb;
    }
    __syncthreads();   // v reused next step; also drains stores before next poll
  }
}

// ---------------- fused head: relu(h*fc1^T+b1)*fc2^T+b2 via bf16 MFMA -------
__global__ __launch_bounds__(512) void head_kernel(
    const ushort_t* __restrict__ h_seq,
    const ushort_t* __restrict__ fc1w,   // [n][k] bf16
    const ushort_t* __restrict__ fc2w,   // [n][k] bf16
    const float* __restrict__ fc1b,
    const float* __restrict__ fc2b,
    float* __restrict__ out) {
  __shared__ __align__(16) ushort_t h1[64 * 512];
  int blk = blockIdx.x;          // 825 blocks, 64 rows each
  int tid = threadIdx.x;
  int w = tid >> 6, l = tid & 63;
  int lm = l & 15, lq = l >> 4;
  int mt = w & 3;                // m-tile within the 64-row block
  int nb = (w >> 2) * 256;       // this wave's n-range
  int m0 = blk * 64;

  // stage 1: h1 = relu(h*fc1^T + b1)
  f32x4 acc[16];
  #pragma unroll
  for (int i = 0; i < 16; ++i) acc[i] = (f32x4){0.f, 0.f, 0.f, 0.f};
  const ushort_t* arow = h_seq + (size_t)(m0 + mt * 16 + lm) * 512;
  for (int kt = 0; kt < 16; ++kt) {
    short8 a = *(const short8*)(arow + kt * 32 + lq * 8);
    #pragma unroll
    for (int nt = 0; nt < 16; ++nt) {
      short8 bb = *(const short8*)(fc1w + (size_t)(nb + nt * 16 + lm) * 512 + kt * 32 + lq * 8);
      acc[nt] = __builtin_amdgcn_mfma_f32_16x16x32_bf16(a, bb, acc[nt], 0, 0, 0);
    }
  }
  #pragma unroll
  for (int nt = 0; nt < 16; ++nt) {
    int n = nb + nt * 16 + lm;
    float bias = fc1b[n];
    #pragma unroll
    for (int r = 0; r < 4; ++r) {
      int m = mt * 16 + lq * 4 + r;
      float vv = acc[nt][r] + bias;
      vv = fmaxf(vv, 0.f);
      h1[m * 512 + n] = f2b(vv);
    }
  }
  __syncthreads();
  // stage 2: out = h1*fc2^T + b2
  f32x4 acc2[16];
  #pragma unroll
  for (int i = 0; i < 16; ++i) acc2[i] = (f32x4){0.f, 0.f, 0.f, 0.f};
  for (int kt = 0; kt < 16; ++kt) {
    short8 a = *(const short8*)&h1[(mt * 16 + lm) * 512 + kt * 32 + lq * 8];
    #pragma unroll
    for (int nt = 0; nt < 16; ++nt) {
      short8 bb = *(const short8*)(fc2w + (size_t)(nb + nt * 16 + lm) * 512 + kt * 32 + lq * 8);
      acc2[nt] = __builtin_amdgcn_mfma_f32_16x16x32_bf16(a, bb, acc2[nt], 0, 0, 0);
    }
  }
  #pragma unroll
  for (int nt = 0; nt < 16; ++nt) {
    int n = nb + nt * 16 + lm;
    float bias = fc2b[n];
    #pragma unroll
    for (int r = 0; r < 4; ++r) {
      int m = mt * 16 + lq * 4 + r;
      out[(size_t)(m0 + m) * 512 + n] = acc2[nt][r] + bias;
    }
  }
}

// ---------------- launch -----------------------------------------------------
extern "C" void kernel_launch(void* const* d_in, const int* in_sizes, int n_in,
                              void* d_out, int out_size, void* d_ws, size_t ws_size,
                              hipStream_t stream) {
  (void)in_sizes; (void)n_in; (void)out_size; (void)ws_size;
  const int*   x    = (const int*)d_in[0];
  const float* mels = (const float*)d_in[1];
  const float* k0   = (const float*)d_in[2];
  const float* k1   = (const float*)d_in[3];
  const float* k2   = (const float*)d_in[4];
  const float* w_ih = (const float*)d_in[5];
  const float* w_hh = (const float*)d_in[6];
  const float* b_ih = (const float*)d_in[7];
  const float* b_hh = (const float*)d_in[8];
  const float* fc1w = (const float*)d_in[9];
  const float* fc1b = (const float*)d_in[10];
  const float* fc2w = (const float*)d_in[11];
  const float* fc2b = (const float*)d_in[12];

  char* ws = (char*)d_ws;
  float*    mels_up = (float*)(ws + 0);           // 16*80*3300*4  = 16,896,000
  ushort_t* h_seq   = (ushort_t*)(ws + 16896000); // 16*3300*512*2 = 54,067,200
  ushort_t* w_ihT   = (ushort_t*)(ws + 70963200); // 512*1536*2    =  1,572,864
  ushort_t* fc1wb   = (ushort_t*)(ws + 72536064); // 512*512*2     =    524,288
  ushort_t* fc2wb   = (ushort_t*)(ws + 73060352); // 512*512*2     =    524,288
  uint32_t* h_ring  = (uint32_t*)(ws + 73584640); // 16*16*512*4   =    524,288
  uint32_t* pctl    = (uint32_t*)(ws + 74108928); // 3*16*16*4     =      3,072

  prep_kernel<<<5635, 256, 0, stream>>>(w_ih, fc1w, fc2w, w_ihT, fc1wb, fc2wb,
                                        h_ring, pctl);
  upsample_kernel<<<1280, 128, 0, stream>>>(mels, k0, k1, k2, mels_up);
  gru_kernel<<<256, 512, 0, stream>>>(x, mels_up, w_ih, w_hh, b_ih, b_hh, w_ihT,
                                      h_ring, pctl, h_seq);
  head_kernel<<<825, 512, 0, stream>>>(h_seq, fc1wb, fc2wb, fc1b, fc2b, (float*)d_out);
}